// Round 5
// baseline (524.704 us; speedup 1.0000x reference)
//
#include <hip/hip_runtime.h>
#include <hip/hip_bf16.h>

typedef unsigned short u16;
typedef unsigned int u32;
typedef __bf16 bf16x8 __attribute__((ext_vector_type(8)));
typedef float f32x4 __attribute__((ext_vector_type(4)));

#define RESOLUTION 7
#define SR 2
#define SS 14
#define NSAMP 196

static __device__ __forceinline__ u16 f2bf(float f) {
    __hip_bfloat16 t = __float2bfloat16(f);
    return *reinterpret_cast<u16*>(&t);
}
static __device__ __forceinline__ float bf2f(u16 h) {
    return __uint_as_float(((u32)h) << 16);
}

// async global->LDS, 16B per lane; lds ptr must be wave-uniform (dest =
// base + lane*16)  [m97/m104-verified pattern]
static __device__ __forceinline__ void load_lds16(const u16* g, u16* l) {
    __builtin_amdgcn_global_load_lds(
        (const __attribute__((address_space(1))) unsigned int*)g,
        (__attribute__((address_space(3))) unsigned int*)l, 16, 0, 0);
}

// ---------------------------------------------------------------------------
// feat (B,C,H,W) f32  ->  (B,HW,C) bf16.  C=256.
// ---------------------------------------------------------------------------
__global__ __launch_bounds__(256) void transpose_feat_kernel(
    const float* __restrict__ in, u16* __restrict__ out, int HW) {
    int b = blockIdx.y;
    int hw0 = blockIdx.x * 64;
    __shared__ u16 tile[256][65];

    int hwo = threadIdx.x & 63;
    int c0 = threadIdx.x >> 6;
    for (int cc = 0; cc < 256; cc += 4) {
        int c = cc + c0;
        float v = in[((size_t)(b * 256 + c)) * HW + hw0 + hwo];
        tile[c][hwo] = f2bf(v);
    }
    __syncthreads();

    int ro = threadIdx.x >> 5;
    int co = (threadIdx.x & 31) * 8;
    for (int i = 0; i < 64; i += 8) {
        int hw = i + ro;
        union { uint4 v; u16 h[8]; } o;
        #pragma unroll
        for (int j = 0; j < 8; ++j) o.h[j] = tile[co + j][hw];
        *(uint4*)&out[((size_t)b * HW + hw0 + hw) * 256 + co] = o.v;
    }
}

// ---------------------------------------------------------------------------
// weight transpose: out (N=1024, K) bf16 = in (K, 1024) f32,
// optional k-permutation  k = (kp&255)*49 + (kp>>8)
// ---------------------------------------------------------------------------
__global__ __launch_bounds__(256) void transpose_w_kernel(
    const float* __restrict__ in, u16* __restrict__ out, int K, int perm) {
    int kp0 = blockIdx.x * 64, n0 = blockIdx.y * 64;
    __shared__ u16 tile[64][65];

    int nn = threadIdx.x & 63, ks = threadIdx.x >> 6;
    for (int i = 0; i < 64; i += 4) {
        int kp = kp0 + ks + i;
        int k = perm ? ((kp & 255) * 49 + (kp >> 8)) : kp;
        tile[ks + i][nn] = f2bf(in[(size_t)k * 1024 + n0 + nn]);
    }
    __syncthreads();

    int nw = threadIdx.x >> 3, ko = (threadIdx.x & 7) * 8;
    for (int i = 0; i < 2; ++i) {
        int n = nw + i * 32;
        union { uint4 v; u16 h[8]; } o;
        #pragma unroll
        for (int j = 0; j < 8; ++j) o.h[j] = tile[ko + j][n];
        *(uint4*)&out[(size_t)(n0 + n) * K + kp0 + ko] = o.v;
    }
}

// ---------------------------------------------------------------------------
// concat head weights -> whT bf16 (128 rows x 1024 k; rows 100..127 zero)
// + bias (100 f32).  col map: [0,4)=cate [4,22)=bbox3d [22,58)=yawc
// [58,94)=yawr [94,100)=hgt
// ---------------------------------------------------------------------------
__global__ void head_concat_kernel(
    const float* __restrict__ cate_w, const float* __restrict__ bbox3d_w,
    const float* __restrict__ yawc_w, const float* __restrict__ yawr_w,
    const float* __restrict__ hgt_w,
    const float* __restrict__ cate_b, const float* __restrict__ bbox3d_b,
    const float* __restrict__ yawc_b, const float* __restrict__ yawr_b,
    const float* __restrict__ hgt_b,
    u16* __restrict__ whT, float* __restrict__ bh) {
    int idx = blockIdx.x * blockDim.x + threadIdx.x;
    if (idx < 128 * 1024) {
        int n = idx >> 10, k = idx & 1023;
        float v = 0.f;
        if (n < 4)        v = cate_w[k * 4 + n];
        else if (n < 22)  v = bbox3d_w[k * 18 + (n - 4)];
        else if (n < 58)  v = yawc_w[k * 36 + (n - 22)];
        else if (n < 94)  v = yawr_w[k * 36 + (n - 58)];
        else if (n < 100) v = hgt_w[k * 6 + (n - 94)];
        whT[idx] = f2bf(v);
    }
    if (idx < 100) {
        int c = idx;
        float v;
        if (c < 4)        v = cate_b[c];
        else if (c < 22)  v = bbox3d_b[c - 4];
        else if (c < 58)  v = yawc_b[c - 22];
        else if (c < 94)  v = yawr_b[c - 58];
        else              v = hgt_b[c - 94];
        bh[c] = v;
    }
}

// ---------------------------------------------------------------------------
// ROI align v2 on (B,HW,C) bf16 feats.  x row layout: k' = bin*256 + c.
// ---------------------------------------------------------------------------
__global__ __launch_bounds__(256) void roi_align_v2_kernel(
    const u16* __restrict__ tf0, const u16* __restrict__ tf1,
    const u16* __restrict__ tf2, const float* __restrict__ bbox2d,
    const int* __restrict__ anchor_id, u16* __restrict__ xb) {
    int bn = blockIdx.x;
    int b = bn >> 9;
    int tid = threadIdx.x;

    __shared__ int s_o00[NSAMP], s_o01[NSAMP], s_o10[NSAMP], s_o11[NSAMP];
    __shared__ float s_w00[NSAMP], s_w01[NSAMP], s_w10[NSAMP], s_w11[NSAMP];

    float cy = bbox2d[bn * 4 + 0], cx = bbox2d[bn * 4 + 1];
    float hh = bbox2d[bn * 4 + 2], ww = bbox2d[bn * 4 + 3];
    int lvl = anchor_id[bn] / 3;
    float scale = (lvl == 0) ? 0.25f : ((lvl == 1) ? 0.125f : 0.0625f);
    int H = (lvl == 0) ? 128 : ((lvl == 1) ? 64 : 32);
    int W = H;

    float t = cy - hh * 0.5f, l = cx - ww * 0.5f;
    float btm = cy + hh * 0.5f, r = cx + ww * 0.5f;
    float sy = t * scale - 0.5f, sx = l * scale - 0.5f;
    float bh = (btm - t) * scale * (1.0f / RESOLUTION);
    float bw = (r - l) * scale * (1.0f / RESOLUTION);

    if (tid < NSAMP) {
        int i = tid / SS, j = tid % SS;
        float gi = (i + 0.5f) * (1.0f / SR);
        float gj = (j + 0.5f) * (1.0f / SR);
        float y = sy + gi * bh, x = sx + gj * bw;
        float valid = (y > -1.0f && y < (float)H && x > -1.0f && x < (float)W)
                          ? 0.25f : 0.0f;
        y = fminf(fmaxf(y, 0.0f), (float)(H - 1));
        x = fminf(fmaxf(x, 0.0f), (float)(W - 1));
        int y0 = (int)floorf(y), x0 = (int)floorf(x);
        int y1 = min(y0 + 1, H - 1), x1 = min(x0 + 1, W - 1);
        float ly = y - (float)y0, lx = x - (float)x0;
        float hy = 1.f - ly, hx = 1.f - lx;
        s_o00[tid] = (y0 * W + x0) * 256;
        s_o01[tid] = (y0 * W + x1) * 256;
        s_o10[tid] = (y1 * W + x0) * 256;
        s_o11[tid] = (y1 * W + x1) * 256;
        s_w00[tid] = hy * hx * valid;
        s_w01[tid] = hy * lx * valid;
        s_w10[tid] = ly * hx * valid;
        s_w11[tid] = ly * lx * valid;
    }
    __syncthreads();

    const u16* fb = (lvl == 0) ? (tf0 + (size_t)b * 16384 * 256)
                  : (lvl == 1) ? (tf1 + (size_t)b * 4096 * 256)
                               : (tf2 + (size_t)b * 1024 * 256);
    int g = tid >> 5;
    int c0 = (tid & 31) * 8;
    u16* xr = xb + (size_t)bn * 12544;

    for (int ii = 0; ii < 7; ++ii) {
        int bin = g + ii * 8;
        if (bin >= 49) break;
        int ph = bin / 7, pw = bin % 7;
        float a[8] = {0.f, 0.f, 0.f, 0.f, 0.f, 0.f, 0.f, 0.f};
        #pragma unroll
        for (int dy = 0; dy < SR; ++dy) {
            #pragma unroll
            for (int dx = 0; dx < SR; ++dx) {
                int si = (ph * SR + dy) * SS + (pw * SR + dx);
                int o00 = s_o00[si], o01 = s_o01[si];
                int o10 = s_o10[si], o11 = s_o11[si];
                float w00 = s_w00[si], w01 = s_w01[si];
                float w10 = s_w10[si], w11 = s_w11[si];
                union { uint4 v; u16 h[8]; } u0, u1, u2, u3;
                u0.v = *(const uint4*)(fb + o00 + c0);
                u1.v = *(const uint4*)(fb + o01 + c0);
                u2.v = *(const uint4*)(fb + o10 + c0);
                u3.v = *(const uint4*)(fb + o11 + c0);
                #pragma unroll
                for (int j = 0; j < 8; ++j) {
                    a[j] = fmaf(bf2f(u0.h[j]), w00, a[j]);
                    a[j] = fmaf(bf2f(u1.h[j]), w01, a[j]);
                    a[j] = fmaf(bf2f(u2.h[j]), w10, a[j]);
                    a[j] = fmaf(bf2f(u3.h[j]), w11, a[j]);
                }
            }
        }
        union { uint4 v; u16 h[8]; } o;
        #pragma unroll
        for (int j = 0; j < 8; ++j) o.h[j] = f2bf(a[j]);
        *(uint4*)&xr[bin * 256 + c0] = o.v;
    }
}

// ---------------------------------------------------------------------------
// zero fill (float4)
// ---------------------------------------------------------------------------
__global__ void zero_kernel(float4* __restrict__ p, int n4) {
    int idx = blockIdx.x * blockDim.x + threadIdx.x;
    if (idx < n4) p[idx] = make_float4(0.f, 0.f, 0.f, 0.f);
}

// ---------------------------------------------------------------------------
// hout(2048,128) init: bias for n<100, 0 above
// ---------------------------------------------------------------------------
__global__ void bias_init_kernel(float* __restrict__ hout,
                                 const float* __restrict__ bh, int total) {
    int idx = blockIdx.x * blockDim.x + threadIdx.x;
    if (idx >= total) return;
    int n = idx & 127;
    hout[idx] = (n < 100) ? bh[n] : 0.f;
}

// ---------------------------------------------------------------------------
// copy hout(2048,128) cols [0,100) -> d_out(2048,100)
// ---------------------------------------------------------------------------
__global__ void copy100_kernel(const float* __restrict__ hout,
                               float* __restrict__ out, int total) {
    int idx = blockIdx.x * blockDim.x + threadIdx.x;
    if (idx >= total) return;
    int m = idx / 100, n = idx - m * 100;
    out[idx] = hout[m * 128 + n];
}

// ---------------------------------------------------------------------------
// m97-style 128x128 MFMA GEMM with split-K + atomic accumulation.
// Y(M,N) += A(M,K-chunk) @ BT(N,K-chunk)^T    (Y pre-initialized)
// ---------------------------------------------------------------------------
__global__ __launch_bounds__(256) void gemm_splitk_kernel(
    const u16* __restrict__ A, const u16* __restrict__ BT,
    float* __restrict__ Y, int M, int N, int K, int KC) {
    __shared__ u16 la[128 * 32];
    __shared__ u16 lb[128 * 32];
    int m0 = blockIdx.x * 128;
    int n0 = blockIdx.y * 128;
    int kbeg = blockIdx.z * KC;
    int tid = threadIdx.x;
    int w = tid >> 6, lane = tid & 63;
    int wm = (w >> 1) * 64, wn = (w & 1) * 64;

    int idx1 = tid + 256;
    const u16* gA0 = A + (size_t)(m0 + (tid >> 2)) * K + (tid & 3) * 8 + kbeg;
    const u16* gA1 = A + (size_t)(m0 + (idx1 >> 2)) * K + (idx1 & 3) * 8 + kbeg;
    const u16* gB0 = BT + (size_t)(n0 + (tid >> 2)) * K + (tid & 3) * 8 + kbeg;
    const u16* gB1 = BT + (size_t)(n0 + (idx1 >> 2)) * K + (idx1 & 3) * 8 + kbeg;
    u16* lA0 = la + w * 512;
    u16* lA1 = la + 2048 + w * 512;
    u16* lB0 = lb + w * 512;
    u16* lB1 = lb + 2048 + w * 512;

    f32x4 acc[4][4] = {};
    int row16 = lane & 15, q8 = (lane >> 4) * 8;

    for (int k0 = 0; k0 < KC; k0 += 32) {
        load_lds16(gA0 + k0, lA0);
        load_lds16(gA1 + k0, lA1);
        load_lds16(gB0 + k0, lB0);
        load_lds16(gB1 + k0, lB1);
        __syncthreads();

        bf16x8 af[4], bf[4];
        #pragma unroll
        for (int tm = 0; tm < 4; ++tm)
            af[tm] = *(const bf16x8*)&la[(wm + tm * 16 + row16) * 32 + q8];
        #pragma unroll
        for (int tn = 0; tn < 4; ++tn)
            bf[tn] = *(const bf16x8*)&lb[(wn + tn * 16 + row16) * 32 + q8];
        #pragma unroll
        for (int tm = 0; tm < 4; ++tm)
            #pragma unroll
            for (int tn = 0; tn < 4; ++tn)
                acc[tm][tn] = __builtin_amdgcn_mfma_f32_16x16x32_bf16(
                    af[tm], bf[tn], acc[tm][tn], 0, 0, 0);
        __syncthreads();
    }

    int col = lane & 15, qr = lane >> 4;
    #pragma unroll
    for (int tm = 0; tm < 4; ++tm) {
        #pragma unroll
        for (int tn = 0; tn < 4; ++tn) {
            int nn = n0 + wn + tn * 16 + col;
            #pragma unroll
            for (int rg = 0; rg < 4; ++rg) {
                int mm = m0 + wm + tm * 16 + qr * 4 + rg;
                unsafeAtomicAdd(&Y[(size_t)mm * N + nn], acc[tm][tn][rg]);
            }
        }
    }
}

// ---------------------------------------------------------------------------
// BN stats stage 1: partial sum/sumsq per 32-row chunk.
// ---------------------------------------------------------------------------
__global__ __launch_bounds__(256) void bn_stats_part_kernel(
    const float* __restrict__ y, float* __restrict__ part, int N) {
    int c4 = blockIdx.x * 256 + (threadIdx.x & 63) * 4;
    int rg = threadIdx.x >> 6;
    int r0 = blockIdx.y * 32;
    float4 s = make_float4(0.f, 0.f, 0.f, 0.f);
    float4 q = make_float4(0.f, 0.f, 0.f, 0.f);
    for (int i = 0; i < 8; ++i) {
        int r = r0 + rg + i * 4;
        float4 v = *(const float4*)&y[(size_t)r * N + c4];
        s.x += v.x; s.y += v.y; s.z += v.z; s.w += v.w;
        q.x += v.x * v.x; q.y += v.y * v.y; q.z += v.z * v.z; q.w += v.w * v.w;
    }
    __shared__ float4 ls[4][64], lq[4][64];
    ls[rg][threadIdx.x & 63] = s;
    lq[rg][threadIdx.x & 63] = q;
    __syncthreads();
    if (rg == 0) {
        int cx = threadIdx.x & 63;
        #pragma unroll
        for (int g = 1; g < 4; ++g) {
            float4 a = ls[g][cx], b = lq[g][cx];
            s.x += a.x; s.y += a.y; s.z += a.z; s.w += a.w;
            q.x += b.x; q.y += b.y; q.z += b.z; q.w += b.w;
        }
        float* po = part + (size_t)blockIdx.y * 2048;
        *(float4*)&po[c4] = s;
        *(float4*)&po[1024 + c4] = q;
    }
}

// ---------------------------------------------------------------------------
// BN stats stage 2: reduce chunks -> mean, rstd.
// ---------------------------------------------------------------------------
__global__ __launch_bounds__(256) void bn_stats_final_kernel(
    const float* __restrict__ part, float* __restrict__ stats, int M, int nchunk) {
    int col = blockIdx.x * 256 + threadIdx.x;
    float s = 0.f, q = 0.f;
    for (int ch = 0; ch < nchunk; ++ch) {
        s += part[(size_t)ch * 2048 + col];
        q += part[(size_t)ch * 2048 + 1024 + col];
    }
    float mean = s / (float)M;
    float var = q / (float)M - mean * mean;
    stats[col] = mean;
    stats[1024 + col] = rsqrtf(var + 1e-5f);
}

// ---------------------------------------------------------------------------
// BN apply + relu -> bf16.  N hardcoded 1024.
// ---------------------------------------------------------------------------
__global__ void bn_apply_kernel(const float* __restrict__ y,
                                const float* __restrict__ stats,
                                const float* __restrict__ g,
                                const float* __restrict__ b,
                                __hip_bfloat16* __restrict__ xo, int total) {
    int idx = blockIdx.x * blockDim.x + threadIdx.x;
    if (idx >= total) return;
    int col = idx & 1023;
    float v = (y[idx] - stats[col]) * stats[1024 + col] * g[col] + b[col];
    xo[idx] = __float2bfloat16(fmaxf(v, 0.f));
}

// ---------------------------------------------------------------------------
extern "C" void kernel_launch(void* const* d_in, const int* in_sizes, int n_in,
                              void* d_out, int out_size, void* d_ws, size_t ws_size,
                              hipStream_t stream) {
    const float* feat0   = (const float*)d_in[0];
    const float* feat1   = (const float*)d_in[1];
    const float* feat2   = (const float*)d_in[2];
    const float* bbox2d  = (const float*)d_in[3];
    const int*   anchor  = (const int*)d_in[4];
    const float* fc1_w   = (const float*)d_in[5];
    const float* bn1_g   = (const float*)d_in[7];
    const float* bn1_b   = (const float*)d_in[8];
    const float* fc2_w   = (const float*)d_in[9];
    const float* bn2_g   = (const float*)d_in[11];
    const float* bn2_b   = (const float*)d_in[12];
    const float* cate_w  = (const float*)d_in[13];
    const float* cate_b  = (const float*)d_in[14];
    const float* bbox3d_w= (const float*)d_in[15];
    const float* bbox3d_b= (const float*)d_in[16];
    const float* yawc_w  = (const float*)d_in[17];
    const float* yawc_b  = (const float*)d_in[18];
    const float* yawr_w  = (const float*)d_in[19];
    const float* yawr_b  = (const float*)d_in[20];
    const float* hgt_w   = (const float*)d_in[21];
    const float* hgt_b   = (const float*)d_in[22];

    const int B = 4, N = 512, FC = 1024;
    const int M = B * N;   // 2048
    const int K1 = 12544;  // 256*49

    // workspace layout (tf* aliased with post-ROI buffers; disjoint lifetimes)
    char* base = (char*)d_ws;
    u16* xb = (u16*)base;                              // 51,380,224 B
    char* ub = base + 51380224;                        // union, 44,040,192 B
    u16* tf0 = (u16*)ub;                               // 33,554,432
    u16* tf1 = (u16*)(ub + 33554432);                  //  8,388,608
    u16* tf2 = (u16*)(ub + 41943040);                  //  2,097,152
    u16* w1t = (u16*)ub;                               // 25,690,112
    u16* w2t = (u16*)(ub + 25690112);                  //  2,097,152
    float* y   = (float*)(ub + 27787264);              //  8,388,608
    u16* x1b = (u16*)(ub + 36175872);                  //  4,194,304 (end 40,370,176)
    float* part = (float*)(ub + 40370176);             //    524,288 (end 40,894,464)
    float* hout = (float*)(ub + 40894464);             //  1,048,576 (dead tf2-gap, used post-roi)
    char* tail = ub + 44040192;
    float* stats = (float*)tail;                       // 8 KB
    u16*   whT   = (u16*)(tail + 8192);                // 262,144 (128x1024 bf16)
    float* bhd   = (float*)(tail + 8192 + 262144);     // 512
    float* outp  = (float*)d_out;

    // 1. head weight concat -> whT bf16 + bias (independent)
    head_concat_kernel<<<(128 * 1024 + 255) / 256, 256, 0, stream>>>(
        cate_w, bbox3d_w, yawc_w, yawr_w, hgt_w,
        cate_b, bbox3d_b, yawc_b, yawr_b, hgt_b, whT, bhd);

    // 2. feature layout transform (B,C,H,W)f32 -> (B,HW,C)bf16
    transpose_feat_kernel<<<dim3(16384 / 64, B), 256, 0, stream>>>(feat0, tf0, 16384);
    transpose_feat_kernel<<<dim3(4096 / 64, B),  256, 0, stream>>>(feat1, tf1, 4096);
    transpose_feat_kernel<<<dim3(1024 / 64, B),  256, 0, stream>>>(feat2, tf2, 1024);

    // 3. ROI align -> x bf16 (M, K1), k' = bin*256 + c layout
    roi_align_v2_kernel<<<M, 256, 0, stream>>>(tf0, tf1, tf2, bbox2d, anchor, xb);

    // 4. weight transposes (overwrite tf* region — after roi)
    transpose_w_kernel<<<dim3(K1 / 64, FC / 64), 256, 0, stream>>>(fc1_w, w1t, K1, 1);
    transpose_w_kernel<<<dim3(FC / 64, FC / 64), 256, 0, stream>>>(fc2_w, w2t, FC, 0);

    // 5. fc1 (split-K=8, atomic accumulate into zeroed y) + BN1
    zero_kernel<<<(M * FC / 4 + 255) / 256, 256, 0, stream>>>((float4*)y, M * FC / 4);
    gemm_splitk_kernel<<<dim3(M / 128, FC / 128, 8), 256, 0, stream>>>(
        xb, w1t, y, M, FC, K1, K1 / 8);
    bn_stats_part_kernel<<<dim3(FC / 256, M / 32), 256, 0, stream>>>(y, part, FC);
    bn_stats_final_kernel<<<FC / 256, 256, 0, stream>>>(part, stats, M, M / 32);
    bn_apply_kernel<<<(M * FC + 255) / 256, 256, 0, stream>>>(
        y, stats, bn1_g, bn1_b, (__hip_bfloat16*)x1b, M * FC);

    // 6. fc2 (split-K=8) + BN2
    zero_kernel<<<(M * FC / 4 + 255) / 256, 256, 0, stream>>>((float4*)y, M * FC / 4);
    gemm_splitk_kernel<<<dim3(M / 128, FC / 128, 8), 256, 0, stream>>>(
        x1b, w2t, y, M, FC, FC, FC / 8);
    bn_stats_part_kernel<<<dim3(FC / 256, M / 32), 256, 0, stream>>>(y, part, FC);
    bn_stats_final_kernel<<<FC / 256, 256, 0, stream>>>(part, stats, M, M / 32);
    bn_apply_kernel<<<(M * FC + 255) / 256, 256, 0, stream>>>(
        y, stats, bn2_g, bn2_b, (__hip_bfloat16*)x1b, M * FC);

    // 7. heads via MFMA: hout = bias; hout += x1b @ whT^T; copy 100 cols
    bias_init_kernel<<<(M * 128 + 255) / 256, 256, 0, stream>>>(hout, bhd, M * 128);
    gemm_splitk_kernel<<<dim3(M / 128, 1, 8), 256, 0, stream>>>(
        x1b, whT, hout, M, 128, FC, FC / 8);
    copy100_kernel<<<(M * 100 + 255) / 256, 256, 0, stream>>>(hout, outp, M * 100);
}

// Round 6
// 466.610 us; speedup vs baseline: 1.1245x; 1.1245x over previous
//
#include <hip/hip_runtime.h>
#include <hip/hip_bf16.h>

typedef unsigned short u16;
typedef unsigned int u32;
typedef __bf16 bf16x8 __attribute__((ext_vector_type(8)));
typedef float f32x4 __attribute__((ext_vector_type(4)));

#define RESOLUTION 7
#define SR 2
#define SS 14
#define NSAMP 196

static __device__ __forceinline__ u16 f2bf(float f) {
    __hip_bfloat16 t = __float2bfloat16(f);
    return *reinterpret_cast<u16*>(&t);
}
static __device__ __forceinline__ float bf2f(u16 h) {
    return __uint_as_float(((u32)h) << 16);
}

// async global->LDS, 16B per lane; lds dest is wave-uniform base + lane*16
// [m97/m104-verified pattern]
static __device__ __forceinline__ void load_lds16(const u16* g, u16* l) {
    __builtin_amdgcn_global_load_lds(
        (const __attribute__((address_space(1))) unsigned int*)g,
        (__attribute__((address_space(3))) unsigned int*)l, 16, 0, 0);
}

// ---------------------------------------------------------------------------
// fused feat transpose: (B,C,H,W) f32 -> (B,HW,C) bf16 for all 3 levels.
// x-blocks: [0,256) f0, [256,320) f1, [320,336) f2.
// ---------------------------------------------------------------------------
__global__ __launch_bounds__(256) void transpose_feat3_kernel(
    const float* __restrict__ f0, const float* __restrict__ f1,
    const float* __restrict__ f2, u16* __restrict__ tf0,
    u16* __restrict__ tf1, u16* __restrict__ tf2) {
    int b = blockIdx.y;
    int bx = blockIdx.x;
    const float* in;
    u16* out;
    int HW, hw0;
    if (bx < 256)      { in = f0; out = tf0; HW = 16384; hw0 = bx * 64; }
    else if (bx < 320) { in = f1; out = tf1; HW = 4096;  hw0 = (bx - 256) * 64; }
    else               { in = f2; out = tf2; HW = 1024;  hw0 = (bx - 320) * 64; }

    __shared__ u16 tile[256][65];
    int hwo = threadIdx.x & 63;
    int c0 = threadIdx.x >> 6;
    for (int cc = 0; cc < 256; cc += 4) {
        int c = cc + c0;
        float v = in[((size_t)(b * 256 + c)) * HW + hw0 + hwo];
        tile[c][hwo] = f2bf(v);
    }
    __syncthreads();

    int ro = threadIdx.x >> 5;
    int co = (threadIdx.x & 31) * 8;
    for (int i = 0; i < 64; i += 8) {
        int hw = i + ro;
        union { uint4 v; u16 h[8]; } o;
        #pragma unroll
        for (int j = 0; j < 8; ++j) o.h[j] = tile[co + j][hw];
        *(uint4*)&out[((size_t)b * HW + hw0 + hw) * 256 + co] = o.v;
    }
}

// ---------------------------------------------------------------------------
// weight transpose: out (N=1024, K) bf16 = in (K, 1024) f32,
// optional k-permutation  k = (kp&255)*49 + (kp>>8)
// ---------------------------------------------------------------------------
__global__ __launch_bounds__(256) void transpose_w_kernel(
    const float* __restrict__ in, u16* __restrict__ out, int K, int perm) {
    int kp0 = blockIdx.x * 64, n0 = blockIdx.y * 64;
    __shared__ u16 tile[64][65];

    int nn = threadIdx.x & 63, ks = threadIdx.x >> 6;
    for (int i = 0; i < 64; i += 4) {
        int kp = kp0 + ks + i;
        int k = perm ? ((kp & 255) * 49 + (kp >> 8)) : kp;
        tile[ks + i][nn] = f2bf(in[(size_t)k * 1024 + n0 + nn]);
    }
    __syncthreads();

    int nw = threadIdx.x >> 3, ko = (threadIdx.x & 7) * 8;
    for (int i = 0; i < 2; ++i) {
        int n = nw + i * 32;
        union { uint4 v; u16 h[8]; } o;
        #pragma unroll
        for (int j = 0; j < 8; ++j) o.h[j] = tile[ko + j][n];
        *(uint4*)&out[(size_t)(n0 + n) * K + kp0 + ko] = o.v;
    }
}

// ---------------------------------------------------------------------------
// concat head weights -> whT bf16 (128 rows x 1024 k; rows 100..127 zero)
// + bias (100 f32)
// ---------------------------------------------------------------------------
__global__ void head_concat_kernel(
    const float* __restrict__ cate_w, const float* __restrict__ bbox3d_w,
    const float* __restrict__ yawc_w, const float* __restrict__ yawr_w,
    const float* __restrict__ hgt_w,
    const float* __restrict__ cate_b, const float* __restrict__ bbox3d_b,
    const float* __restrict__ yawc_b, const float* __restrict__ yawr_b,
    const float* __restrict__ hgt_b,
    u16* __restrict__ whT, float* __restrict__ bh) {
    int idx = blockIdx.x * blockDim.x + threadIdx.x;
    if (idx < 128 * 1024) {
        int n = idx >> 10, k = idx & 1023;
        float v = 0.f;
        if (n < 4)        v = cate_w[k * 4 + n];
        else if (n < 22)  v = bbox3d_w[k * 18 + (n - 4)];
        else if (n < 58)  v = yawc_w[k * 36 + (n - 22)];
        else if (n < 94)  v = yawr_w[k * 36 + (n - 58)];
        else if (n < 100) v = hgt_w[k * 6 + (n - 94)];
        whT[idx] = f2bf(v);
    }
    if (idx < 100) {
        int c = idx;
        float v;
        if (c < 4)        v = cate_b[c];
        else if (c < 22)  v = bbox3d_b[c - 4];
        else if (c < 58)  v = yawc_b[c - 22];
        else if (c < 94)  v = yawr_b[c - 58];
        else              v = hgt_b[c - 94];
        bh[c] = v;
    }
}

// ---------------------------------------------------------------------------
// ROI align v3 on (B,HW,C) bf16 feats.  x row layout: k' = bin*256 + c.
// 512 threads = 16 groups of 32 lanes; group g handles bins {g, g+16, g+32}
// (+48 for g==0) -> serial chain of <=4 bins (was 7) for better MLP.
// ---------------------------------------------------------------------------
__global__ __launch_bounds__(512) void roi_align_v3_kernel(
    const u16* __restrict__ tf0, const u16* __restrict__ tf1,
    const u16* __restrict__ tf2, const float* __restrict__ bbox2d,
    const int* __restrict__ anchor_id, u16* __restrict__ xb) {
    int bn = blockIdx.x;
    int b = bn >> 9;
    int tid = threadIdx.x;

    __shared__ int s_o00[NSAMP], s_o01[NSAMP], s_o10[NSAMP], s_o11[NSAMP];
    __shared__ float s_w00[NSAMP], s_w01[NSAMP], s_w10[NSAMP], s_w11[NSAMP];

    float cy = bbox2d[bn * 4 + 0], cx = bbox2d[bn * 4 + 1];
    float hh = bbox2d[bn * 4 + 2], ww = bbox2d[bn * 4 + 3];
    int lvl = anchor_id[bn] / 3;
    float scale = (lvl == 0) ? 0.25f : ((lvl == 1) ? 0.125f : 0.0625f);
    int H = (lvl == 0) ? 128 : ((lvl == 1) ? 64 : 32);
    int W = H;

    float t = cy - hh * 0.5f, l = cx - ww * 0.5f;
    float btm = cy + hh * 0.5f, r = cx + ww * 0.5f;
    float sy = t * scale - 0.5f, sx = l * scale - 0.5f;
    float bh = (btm - t) * scale * (1.0f / RESOLUTION);
    float bw = (r - l) * scale * (1.0f / RESOLUTION);

    if (tid < NSAMP) {
        int i = tid / SS, j = tid % SS;
        float gi = (i + 0.5f) * (1.0f / SR);
        float gj = (j + 0.5f) * (1.0f / SR);
        float y = sy + gi * bh, x = sx + gj * bw;
        float valid = (y > -1.0f && y < (float)H && x > -1.0f && x < (float)W)
                          ? 0.25f : 0.0f;
        y = fminf(fmaxf(y, 0.0f), (float)(H - 1));
        x = fminf(fmaxf(x, 0.0f), (float)(W - 1));
        int y0 = (int)floorf(y), x0 = (int)floorf(x);
        int y1 = min(y0 + 1, H - 1), x1 = min(x0 + 1, W - 1);
        float ly = y - (float)y0, lx = x - (float)x0;
        float hy = 1.f - ly, hx = 1.f - lx;
        s_o00[tid] = (y0 * W + x0) * 256;
        s_o01[tid] = (y0 * W + x1) * 256;
        s_o10[tid] = (y1 * W + x0) * 256;
        s_o11[tid] = (y1 * W + x1) * 256;
        s_w00[tid] = hy * hx * valid;
        s_w01[tid] = hy * lx * valid;
        s_w10[tid] = ly * hx * valid;
        s_w11[tid] = ly * lx * valid;
    }
    __syncthreads();

    const u16* fb = (lvl == 0) ? (tf0 + (size_t)b * 16384 * 256)
                  : (lvl == 1) ? (tf1 + (size_t)b * 4096 * 256)
                               : (tf2 + (size_t)b * 1024 * 256);
    int g = tid >> 5;
    int c0 = (tid & 31) * 8;
    u16* xr = xb + (size_t)bn * 12544;

    #pragma unroll
    for (int ii = 0; ii < 4; ++ii) {
        int bin = g + ii * 16;
        if (bin < 49) {
            int ph = bin / 7, pw = bin % 7;
            float a[8] = {0.f, 0.f, 0.f, 0.f, 0.f, 0.f, 0.f, 0.f};
            #pragma unroll
            for (int dy = 0; dy < SR; ++dy) {
                #pragma unroll
                for (int dx = 0; dx < SR; ++dx) {
                    int si = (ph * SR + dy) * SS + (pw * SR + dx);
                    int o00 = s_o00[si], o01 = s_o01[si];
                    int o10 = s_o10[si], o11 = s_o11[si];
                    float w00 = s_w00[si], w01 = s_w01[si];
                    float w10 = s_w10[si], w11 = s_w11[si];
                    union { uint4 v; u16 h[8]; } u0, u1, u2, u3;
                    u0.v = *(const uint4*)(fb + o00 + c0);
                    u1.v = *(const uint4*)(fb + o01 + c0);
                    u2.v = *(const uint4*)(fb + o10 + c0);
                    u3.v = *(const uint4*)(fb + o11 + c0);
                    #pragma unroll
                    for (int j = 0; j < 8; ++j) {
                        a[j] = fmaf(bf2f(u0.h[j]), w00, a[j]);
                        a[j] = fmaf(bf2f(u1.h[j]), w01, a[j]);
                        a[j] = fmaf(bf2f(u2.h[j]), w10, a[j]);
                        a[j] = fmaf(bf2f(u3.h[j]), w11, a[j]);
                    }
                }
            }
            union { uint4 v; u16 h[8]; } o;
            #pragma unroll
            for (int j = 0; j < 8; ++j) o.h[j] = f2bf(a[j]);
            *(uint4*)&xr[bin * 256 + c0] = o.v;
        }
    }
}

// ---------------------------------------------------------------------------
// zero fill (float4)
// ---------------------------------------------------------------------------
__global__ void zero_kernel(float4* __restrict__ p, int n4) {
    int idx = blockIdx.x * blockDim.x + threadIdx.x;
    if (idx < n4) p[idx] = make_float4(0.f, 0.f, 0.f, 0.f);
}

// ---------------------------------------------------------------------------
// hout(2048,128) init: bias for n<100, 0 above
// ---------------------------------------------------------------------------
__global__ void bias_init_kernel(float* __restrict__ hout,
                                 const float* __restrict__ bh, int total) {
    int idx = blockIdx.x * blockDim.x + threadIdx.x;
    if (idx >= total) return;
    int n = idx & 127;
    hout[idx] = (n < 100) ? bh[n] : 0.f;
}

// ---------------------------------------------------------------------------
// copy hout(2048,128) cols [0,100) -> d_out(2048,100)
// ---------------------------------------------------------------------------
__global__ void copy100_kernel(const float* __restrict__ hout,
                               float* __restrict__ out, int total) {
    int idx = blockIdx.x * blockDim.x + threadIdx.x;
    if (idx >= total) return;
    int m = idx / 100, n = idx - m * 100;
    out[idx] = hout[m * 128 + n];
}

// ---------------------------------------------------------------------------
// m97-style 128x128 MFMA GEMM with split-K + atomic accumulation.
// Y(M,N) += A(M,K-chunk) @ BT(N,K-chunk)^T    (Y pre-initialized)
// split-K=4 is the measured sweet spot (z=8 regressed: chain-end overhead
// + 2x atomic churn beat the occupancy gain — R5 post-mortem).
// ---------------------------------------------------------------------------
__global__ __launch_bounds__(256) void gemm_splitk_kernel(
    const u16* __restrict__ A, const u16* __restrict__ BT,
    float* __restrict__ Y, int M, int N, int K, int KC) {
    __shared__ u16 la[128 * 32];
    __shared__ u16 lb[128 * 32];
    int m0 = blockIdx.x * 128;
    int n0 = blockIdx.y * 128;
    int kbeg = blockIdx.z * KC;
    int tid = threadIdx.x;
    int w = tid >> 6, lane = tid & 63;
    int wm = (w >> 1) * 64, wn = (w & 1) * 64;

    int idx1 = tid + 256;
    const u16* gA0 = A + (size_t)(m0 + (tid >> 2)) * K + (tid & 3) * 8 + kbeg;
    const u16* gA1 = A + (size_t)(m0 + (idx1 >> 2)) * K + (idx1 & 3) * 8 + kbeg;
    const u16* gB0 = BT + (size_t)(n0 + (tid >> 2)) * K + (tid & 3) * 8 + kbeg;
    const u16* gB1 = BT + (size_t)(n0 + (idx1 >> 2)) * K + (idx1 & 3) * 8 + kbeg;
    u16* lA0 = la + w * 512;
    u16* lA1 = la + 2048 + w * 512;
    u16* lB0 = lb + w * 512;
    u16* lB1 = lb + 2048 + w * 512;

    f32x4 acc[4][4] = {};
    int row16 = lane & 15, q8 = (lane >> 4) * 8;

    for (int k0 = 0; k0 < KC; k0 += 32) {
        load_lds16(gA0 + k0, lA0);
        load_lds16(gA1 + k0, lA1);
        load_lds16(gB0 + k0, lB0);
        load_lds16(gB1 + k0, lB1);
        __syncthreads();

        bf16x8 af[4], bf[4];
        #pragma unroll
        for (int tm = 0; tm < 4; ++tm)
            af[tm] = *(const bf16x8*)&la[(wm + tm * 16 + row16) * 32 + q8];
        #pragma unroll
        for (int tn = 0; tn < 4; ++tn)
            bf[tn] = *(const bf16x8*)&lb[(wn + tn * 16 + row16) * 32 + q8];
        #pragma unroll
        for (int tm = 0; tm < 4; ++tm)
            #pragma unroll
            for (int tn = 0; tn < 4; ++tn)
                acc[tm][tn] = __builtin_amdgcn_mfma_f32_16x16x32_bf16(
                    af[tm], bf[tn], acc[tm][tn], 0, 0, 0);
        __syncthreads();
    }

    int col = lane & 15, qr = lane >> 4;
    #pragma unroll
    for (int tm = 0; tm < 4; ++tm) {
        #pragma unroll
        for (int tn = 0; tn < 4; ++tn) {
            int nn = n0 + wn + tn * 16 + col;
            #pragma unroll
            for (int rg = 0; rg < 4; ++rg) {
                int mm = m0 + wm + tm * 16 + qr * 4 + rg;
                unsafeAtomicAdd(&Y[(size_t)mm * N + nn], acc[tm][tn][rg]);
            }
        }
    }
}

// ---------------------------------------------------------------------------
// BN stats stage 1: partial sum/sumsq per 32-row chunk.
// ---------------------------------------------------------------------------
__global__ __launch_bounds__(256) void bn_stats_part_kernel(
    const float* __restrict__ y, float* __restrict__ part, int N) {
    int c4 = blockIdx.x * 256 + (threadIdx.x & 63) * 4;
    int rg = threadIdx.x >> 6;
    int r0 = blockIdx.y * 32;
    float4 s = make_float4(0.f, 0.f, 0.f, 0.f);
    float4 q = make_float4(0.f, 0.f, 0.f, 0.f);
    for (int i = 0; i < 8; ++i) {
        int r = r0 + rg + i * 4;
        float4 v = *(const float4*)&y[(size_t)r * N + c4];
        s.x += v.x; s.y += v.y; s.z += v.z; s.w += v.w;
        q.x += v.x * v.x; q.y += v.y * v.y; q.z += v.z * v.z; q.w += v.w * v.w;
    }
    __shared__ float4 ls[4][64], lq[4][64];
    ls[rg][threadIdx.x & 63] = s;
    lq[rg][threadIdx.x & 63] = q;
    __syncthreads();
    if (rg == 0) {
        int cx = threadIdx.x & 63;
        #pragma unroll
        for (int g = 1; g < 4; ++g) {
            float4 a = ls[g][cx], b = lq[g][cx];
            s.x += a.x; s.y += a.y; s.z += a.z; s.w += a.w;
            q.x += b.x; q.y += b.y; q.z += b.z; q.w += b.w;
        }
        float* po = part + (size_t)blockIdx.y * 2048;
        *(float4*)&po[c4] = s;
        *(float4*)&po[1024 + c4] = q;
    }
}

// ---------------------------------------------------------------------------
// BN stats stage 2: reduce chunks -> mean, rstd.
// ---------------------------------------------------------------------------
__global__ __launch_bounds__(256) void bn_stats_final_kernel(
    const float* __restrict__ part, float* __restrict__ stats, int M, int nchunk) {
    int col = blockIdx.x * 256 + threadIdx.x;
    float s = 0.f, q = 0.f;
    for (int ch = 0; ch < nchunk; ++ch) {
        s += part[(size_t)ch * 2048 + col];
        q += part[(size_t)ch * 2048 + 1024 + col];
    }
    float mean = s / (float)M;
    float var = q / (float)M - mean * mean;
    stats[col] = mean;
    stats[1024 + col] = rsqrtf(var + 1e-5f);
}

// ---------------------------------------------------------------------------
// BN apply + relu -> bf16.  N hardcoded 1024.
// ---------------------------------------------------------------------------
__global__ void bn_apply_kernel(const float* __restrict__ y,
                                const float* __restrict__ stats,
                                const float* __restrict__ g,
                                const float* __restrict__ b,
                                __hip_bfloat16* __restrict__ xo, int total) {
    int idx = blockIdx.x * blockDim.x + threadIdx.x;
    if (idx >= total) return;
    int col = idx & 1023;
    float v = (y[idx] - stats[col]) * stats[1024 + col] * g[col] + b[col];
    xo[idx] = __float2bfloat16(fmaxf(v, 0.f));
}

// ---------------------------------------------------------------------------
extern "C" void kernel_launch(void* const* d_in, const int* in_sizes, int n_in,
                              void* d_out, int out_size, void* d_ws, size_t ws_size,
                              hipStream_t stream) {
    const float* feat0   = (const float*)d_in[0];
    const float* feat1   = (const float*)d_in[1];
    const float* feat2   = (const float*)d_in[2];
    const float* bbox2d  = (const float*)d_in[3];
    const int*   anchor  = (const int*)d_in[4];
    const float* fc1_w   = (const float*)d_in[5];
    const float* bn1_g   = (const float*)d_in[7];
    const float* bn1_b   = (const float*)d_in[8];
    const float* fc2_w   = (const float*)d_in[9];
    const float* bn2_g   = (const float*)d_in[11];
    const float* bn2_b   = (const float*)d_in[12];
    const float* cate_w  = (const float*)d_in[13];
    const float* cate_b  = (const float*)d_in[14];
    const float* bbox3d_w= (const float*)d_in[15];
    const float* bbox3d_b= (const float*)d_in[16];
    const float* yawc_w  = (const float*)d_in[17];
    const float* yawc_b  = (const float*)d_in[18];
    const float* yawr_w  = (const float*)d_in[19];
    const float* yawr_b  = (const float*)d_in[20];
    const float* hgt_w   = (const float*)d_in[21];
    const float* hgt_b   = (const float*)d_in[22];

    const int B = 4, N = 512, FC = 1024;
    const int M = B * N;   // 2048
    const int K1 = 12544;  // 256*49

    // workspace layout (tf* aliased with post-ROI buffers; disjoint lifetimes)
    char* base = (char*)d_ws;
    u16* xb = (u16*)base;                              // 51,380,224 B
    char* ub = base + 51380224;                        // union, 44,040,192 B
    u16* tf0 = (u16*)ub;                               // 33,554,432
    u16* tf1 = (u16*)(ub + 33554432);                  //  8,388,608
    u16* tf2 = (u16*)(ub + 41943040);                  //  2,097,152
    u16* w1t = (u16*)ub;                               // 25,690,112
    u16* w2t = (u16*)(ub + 25690112);                  //  2,097,152
    float* y   = (float*)(ub + 27787264);              //  8,388,608
    u16* x1b = (u16*)(ub + 36175872);                  //  4,194,304 (end 40,370,176)
    float* part = (float*)(ub + 40370176);             //    524,288 (end 40,894,464)
    float* hout = (float*)(ub + 40894464);             //  1,048,576
    char* tail = ub + 44040192;
    float* stats = (float*)tail;                       // 8 KB
    u16*   whT   = (u16*)(tail + 8192);                // 262,144 (128x1024 bf16)
    float* bhd   = (float*)(tail + 8192 + 262144);     // 512
    float* outp  = (float*)d_out;

    // 1. head weight concat -> whT bf16 + bias (independent)
    head_concat_kernel<<<(128 * 1024 + 255) / 256, 256, 0, stream>>>(
        cate_w, bbox3d_w, yawc_w, yawr_w, hgt_w,
        cate_b, bbox3d_b, yawc_b, yawr_b, hgt_b, whT, bhd);

    // 2. fused feature layout transform (B,C,H,W)f32 -> (B,HW,C)bf16
    transpose_feat3_kernel<<<dim3(336, B), 256, 0, stream>>>(
        feat0, feat1, feat2, tf0, tf1, tf2);

    // 3. ROI align -> x bf16 (M, K1), k' = bin*256 + c layout
    roi_align_v3_kernel<<<M, 512, 0, stream>>>(tf0, tf1, tf2, bbox2d, anchor, xb);

    // 4. weight transposes (overwrite tf* region — after roi)
    transpose_w_kernel<<<dim3(K1 / 64, FC / 64), 256, 0, stream>>>(fc1_w, w1t, K1, 1);
    transpose_w_kernel<<<dim3(FC / 64, FC / 64), 256, 0, stream>>>(fc2_w, w2t, FC, 0);

    // 5. fc1 (split-K=4, atomic accumulate into zeroed y) + BN1
    zero_kernel<<<(M * FC / 4 + 255) / 256, 256, 0, stream>>>((float4*)y, M * FC / 4);
    gemm_splitk_kernel<<<dim3(M / 128, FC / 128, 4), 256, 0, stream>>>(
        xb, w1t, y, M, FC, K1, K1 / 4);
    bn_stats_part_kernel<<<dim3(FC / 256, M / 32), 256, 0, stream>>>(y, part, FC);
    bn_stats_final_kernel<<<FC / 256, 256, 0, stream>>>(part, stats, M, M / 32);
    bn_apply_kernel<<<(M * FC + 255) / 256, 256, 0, stream>>>(
        y, stats, bn1_g, bn1_b, (__hip_bfloat16*)x1b, M * FC);

    // 6. fc2 (split-K=4) + BN2
    zero_kernel<<<(M * FC / 4 + 255) / 256, 256, 0, stream>>>((float4*)y, M * FC / 4);
    gemm_splitk_kernel<<<dim3(M / 128, FC / 128, 4), 256, 0, stream>>>(
        x1b, w2t, y, M, FC, FC, FC / 4);
    bn_stats_part_kernel<<<dim3(FC / 256, M / 32), 256, 0, stream>>>(y, part, FC);
    bn_stats_final_kernel<<<FC / 256, 256, 0, stream>>>(part, stats, M, M / 32);
    bn_apply_kernel<<<(M * FC + 255) / 256, 256, 0, stream>>>(
        y, stats, bn2_g, bn2_b, (__hip_bfloat16*)x1b, M * FC);

    // 7. heads via MFMA: hout = bias; hout += x1b @ whT^T; copy 100 cols
    bias_init_kernel<<<(M * 128 + 255) / 256, 256, 0, stream>>>(hout, bhd, M * 128);
    gemm_splitk_kernel<<<dim3(M / 128, 1, 8), 256, 0, stream>>>(
        x1b, whT, hout, M, 128, FC, FC / 8);
    copy100_kernel<<<(M * 100 + 255) / 256, 256, 0, stream>>>(hout, outp, M * 100);
}

// Round 7
// 453.588 us; speedup vs baseline: 1.1568x; 1.0287x over previous
//
#include <hip/hip_runtime.h>
#include <hip/hip_bf16.h>

typedef unsigned short u16;
typedef unsigned int u32;
typedef __bf16 bf16x8 __attribute__((ext_vector_type(8)));
typedef float f32x4 __attribute__((ext_vector_type(4)));

#define RESOLUTION 7
#define SR 2
#define SS 14
#define NSAMP 196

static __device__ __forceinline__ u16 f2bf(float f) {
    __hip_bfloat16 t = __float2bfloat16(f);
    return *reinterpret_cast<u16*>(&t);
}
static __device__ __forceinline__ float bf2f(u16 h) {
    return __uint_as_float(((u32)h) << 16);
}

// async global->LDS, 16B per lane; lds dest is wave-uniform base + lane*16
// [m97/m104-verified pattern]
static __device__ __forceinline__ void load_lds16(const u16* g, u16* l) {
    __builtin_amdgcn_global_load_lds(
        (const __attribute__((address_space(1))) unsigned int*)g,
        (__attribute__((address_space(3))) unsigned int*)l, 16, 0, 0);
}

// ---------------------------------------------------------------------------
// fused feat transpose: (B,C,H,W) f32 -> (B,HW,C) bf16 for all 3 levels.
// ---------------------------------------------------------------------------
__global__ __launch_bounds__(256) void transpose_feat3_kernel(
    const float* __restrict__ f0, const float* __restrict__ f1,
    const float* __restrict__ f2, u16* __restrict__ tf0,
    u16* __restrict__ tf1, u16* __restrict__ tf2) {
    int b = blockIdx.y;
    int bx = blockIdx.x;
    const float* in;
    u16* out;
    int HW, hw0;
    if (bx < 256)      { in = f0; out = tf0; HW = 16384; hw0 = bx * 64; }
    else if (bx < 320) { in = f1; out = tf1; HW = 4096;  hw0 = (bx - 256) * 64; }
    else               { in = f2; out = tf2; HW = 1024;  hw0 = (bx - 320) * 64; }

    __shared__ u16 tile[256][65];
    int hwo = threadIdx.x & 63;
    int c0 = threadIdx.x >> 6;
    for (int cc = 0; cc < 256; cc += 4) {
        int c = cc + c0;
        float v = in[((size_t)(b * 256 + c)) * HW + hw0 + hwo];
        tile[c][hwo] = f2bf(v);
    }
    __syncthreads();

    int ro = threadIdx.x >> 5;
    int co = (threadIdx.x & 31) * 8;
    for (int i = 0; i < 64; i += 8) {
        int hw = i + ro;
        union { uint4 v; u16 h[8]; } o;
        #pragma unroll
        for (int j = 0; j < 8; ++j) o.h[j] = tile[co + j][hw];
        *(uint4*)&out[((size_t)b * HW + hw0 + hw) * 256 + co] = o.v;
    }
}

// ---------------------------------------------------------------------------
// weight transpose: out (N=1024, K) bf16 = in (K, 1024) f32,
// optional k-permutation  k = (kp&255)*49 + (kp>>8)
// ---------------------------------------------------------------------------
__global__ __launch_bounds__(256) void transpose_w_kernel(
    const float* __restrict__ in, u16* __restrict__ out, int K, int perm) {
    int kp0 = blockIdx.x * 64, n0 = blockIdx.y * 64;
    __shared__ u16 tile[64][65];

    int nn = threadIdx.x & 63, ks = threadIdx.x >> 6;
    for (int i = 0; i < 64; i += 4) {
        int kp = kp0 + ks + i;
        int k = perm ? ((kp & 255) * 49 + (kp >> 8)) : kp;
        tile[ks + i][nn] = f2bf(in[(size_t)k * 1024 + n0 + nn]);
    }
    __syncthreads();

    int nw = threadIdx.x >> 3, ko = (threadIdx.x & 7) * 8;
    for (int i = 0; i < 2; ++i) {
        int n = nw + i * 32;
        union { uint4 v; u16 h[8]; } o;
        #pragma unroll
        for (int j = 0; j < 8; ++j) o.h[j] = tile[ko + j][n];
        *(uint4*)&out[(size_t)(n0 + n) * K + kp0 + ko] = o.v;
    }
}

// ---------------------------------------------------------------------------
// concat head weights -> whT bf16 (128 rows x 1024 k; rows 100..127 zero)
// + bias (100 f32)
// ---------------------------------------------------------------------------
__global__ void head_concat_kernel(
    const float* __restrict__ cate_w, const float* __restrict__ bbox3d_w,
    const float* __restrict__ yawc_w, const float* __restrict__ yawr_w,
    const float* __restrict__ hgt_w,
    const float* __restrict__ cate_b, const float* __restrict__ bbox3d_b,
    const float* __restrict__ yawc_b, const float* __restrict__ yawr_b,
    const float* __restrict__ hgt_b,
    u16* __restrict__ whT, float* __restrict__ bh) {
    int idx = blockIdx.x * blockDim.x + threadIdx.x;
    if (idx < 128 * 1024) {
        int n = idx >> 10, k = idx & 1023;
        float v = 0.f;
        if (n < 4)        v = cate_w[k * 4 + n];
        else if (n < 22)  v = bbox3d_w[k * 18 + (n - 4)];
        else if (n < 58)  v = yawc_w[k * 36 + (n - 22)];
        else if (n < 94)  v = yawr_w[k * 36 + (n - 58)];
        else if (n < 100) v = hgt_w[k * 6 + (n - 94)];
        whT[idx] = f2bf(v);
    }
    if (idx < 100) {
        int c = idx;
        float v;
        if (c < 4)        v = cate_b[c];
        else if (c < 22)  v = bbox3d_b[c - 4];
        else if (c < 58)  v = yawc_b[c - 22];
        else if (c < 94)  v = yawr_b[c - 58];
        else              v = hgt_b[c - 94];
        bh[c] = v;
    }
}

// ---------------------------------------------------------------------------
// ROI align v3 on (B,HW,C) bf16 feats.  x row layout: k' = bin*256 + c.
// 512 threads = 16 groups of 32 lanes; <=4 bins per group.
// ---------------------------------------------------------------------------
__global__ __launch_bounds__(512) void roi_align_v3_kernel(
    const u16* __restrict__ tf0, const u16* __restrict__ tf1,
    const u16* __restrict__ tf2, const float* __restrict__ bbox2d,
    const int* __restrict__ anchor_id, u16* __restrict__ xb) {
    int bn = blockIdx.x;
    int b = bn >> 9;
    int tid = threadIdx.x;

    __shared__ int s_o00[NSAMP], s_o01[NSAMP], s_o10[NSAMP], s_o11[NSAMP];
    __shared__ float s_w00[NSAMP], s_w01[NSAMP], s_w10[NSAMP], s_w11[NSAMP];

    float cy = bbox2d[bn * 4 + 0], cx = bbox2d[bn * 4 + 1];
    float hh = bbox2d[bn * 4 + 2], ww = bbox2d[bn * 4 + 3];
    int lvl = anchor_id[bn] / 3;
    float scale = (lvl == 0) ? 0.25f : ((lvl == 1) ? 0.125f : 0.0625f);
    int H = (lvl == 0) ? 128 : ((lvl == 1) ? 64 : 32);
    int W = H;

    float t = cy - hh * 0.5f, l = cx - ww * 0.5f;
    float btm = cy + hh * 0.5f, r = cx + ww * 0.5f;
    float sy = t * scale - 0.5f, sx = l * scale - 0.5f;
    float bh = (btm - t) * scale * (1.0f / RESOLUTION);
    float bw = (r - l) * scale * (1.0f / RESOLUTION);

    if (tid < NSAMP) {
        int i = tid / SS, j = tid % SS;
        float gi = (i + 0.5f) * (1.0f / SR);
        float gj = (j + 0.5f) * (1.0f / SR);
        float y = sy + gi * bh, x = sx + gj * bw;
        float valid = (y > -1.0f && y < (float)H && x > -1.0f && x < (float)W)
                          ? 0.25f : 0.0f;
        y = fminf(fmaxf(y, 0.0f), (float)(H - 1));
        x = fminf(fmaxf(x, 0.0f), (float)(W - 1));
        int y0 = (int)floorf(y), x0 = (int)floorf(x);
        int y1 = min(y0 + 1, H - 1), x1 = min(x0 + 1, W - 1);
        float ly = y - (float)y0, lx = x - (float)x0;
        float hy = 1.f - ly, hx = 1.f - lx;
        s_o00[tid] = (y0 * W + x0) * 256;
        s_o01[tid] = (y0 * W + x1) * 256;
        s_o10[tid] = (y1 * W + x0) * 256;
        s_o11[tid] = (y1 * W + x1) * 256;
        s_w00[tid] = hy * hx * valid;
        s_w01[tid] = hy * lx * valid;
        s_w10[tid] = ly * hx * valid;
        s_w11[tid] = ly * lx * valid;
    }
    __syncthreads();

    const u16* fb = (lvl == 0) ? (tf0 + (size_t)b * 16384 * 256)
                  : (lvl == 1) ? (tf1 + (size_t)b * 4096 * 256)
                               : (tf2 + (size_t)b * 1024 * 256);
    int g = tid >> 5;
    int c0 = (tid & 31) * 8;
    u16* xr = xb + (size_t)bn * 12544;

    #pragma unroll
    for (int ii = 0; ii < 4; ++ii) {
        int bin = g + ii * 16;
        if (bin < 49) {
            int ph = bin / 7, pw = bin % 7;
            float a[8] = {0.f, 0.f, 0.f, 0.f, 0.f, 0.f, 0.f, 0.f};
            #pragma unroll
            for (int dy = 0; dy < SR; ++dy) {
                #pragma unroll
                for (int dx = 0; dx < SR; ++dx) {
                    int si = (ph * SR + dy) * SS + (pw * SR + dx);
                    int o00 = s_o00[si], o01 = s_o01[si];
                    int o10 = s_o10[si], o11 = s_o11[si];
                    float w00 = s_w00[si], w01 = s_w01[si];
                    float w10 = s_w10[si], w11 = s_w11[si];
                    union { uint4 v; u16 h[8]; } u0, u1, u2, u3;
                    u0.v = *(const uint4*)(fb + o00 + c0);
                    u1.v = *(const uint4*)(fb + o01 + c0);
                    u2.v = *(const uint4*)(fb + o10 + c0);
                    u3.v = *(const uint4*)(fb + o11 + c0);
                    #pragma unroll
                    for (int j = 0; j < 8; ++j) {
                        a[j] = fmaf(bf2f(u0.h[j]), w00, a[j]);
                        a[j] = fmaf(bf2f(u1.h[j]), w01, a[j]);
                        a[j] = fmaf(bf2f(u2.h[j]), w10, a[j]);
                        a[j] = fmaf(bf2f(u3.h[j]), w11, a[j]);
                    }
                }
            }
            union { uint4 v; u16 h[8]; } o;
            #pragma unroll
            for (int j = 0; j < 8; ++j) o.h[j] = f2bf(a[j]);
            *(uint4*)&xr[bin * 256 + c0] = o.v;
        }
    }
}

// ---------------------------------------------------------------------------
// hout(2048,128) init: bias for n<100, 0 above
// ---------------------------------------------------------------------------
__global__ void bias_init_kernel(float* __restrict__ hout,
                                 const float* __restrict__ bh, int total) {
    int idx = blockIdx.x * blockDim.x + threadIdx.x;
    if (idx >= total) return;
    int n = idx & 127;
    hout[idx] = (n < 100) ? bh[n] : 0.f;
}

// ---------------------------------------------------------------------------
// copy hout(2048,128) cols [0,100) -> d_out(2048,100)
// ---------------------------------------------------------------------------
__global__ void copy100_kernel(const float* __restrict__ hout,
                               float* __restrict__ out, int total) {
    int idx = blockIdx.x * blockDim.x + threadIdx.x;
    if (idx >= total) return;
    int m = idx / 100, n = idx - m * 100;
    out[idx] = hout[m * 128 + n];
}

// ---------------------------------------------------------------------------
// 128x128 MFMA GEMM, split-K + atomic accumulation, BK=64 double-stage:
// two 32-wide K-slices staged into separate LDS buffer pairs -> 32 MFMAs
// per barrier pair (was 16). 32 KB LDS still allows 5 blocks/CU.
// split-K=4 measured sweet spot (z=8 regressed — R5 post-mortem).
// ---------------------------------------------------------------------------
__global__ __launch_bounds__(256) void gemm_splitk_kernel(
    const u16* __restrict__ A, const u16* __restrict__ BT,
    float* __restrict__ Y, int M, int N, int K, int KC) {
    __shared__ u16 la[2][128 * 32];
    __shared__ u16 lb[2][128 * 32];
    int m0 = blockIdx.x * 128;
    int n0 = blockIdx.y * 128;
    int kbeg = blockIdx.z * KC;
    int tid = threadIdx.x;
    int w = tid >> 6, lane = tid & 63;
    int wm = (w >> 1) * 64, wn = (w & 1) * 64;

    int idx1 = tid + 256;
    const u16* gA0 = A + (size_t)(m0 + (tid >> 2)) * K + (tid & 3) * 8 + kbeg;
    const u16* gA1 = A + (size_t)(m0 + (idx1 >> 2)) * K + (idx1 & 3) * 8 + kbeg;
    const u16* gB0 = BT + (size_t)(n0 + (tid >> 2)) * K + (tid & 3) * 8 + kbeg;
    const u16* gB1 = BT + (size_t)(n0 + (idx1 >> 2)) * K + (idx1 & 3) * 8 + kbeg;
    u16* lA0a = la[0] + w * 512;
    u16* lA1a = la[0] + 2048 + w * 512;
    u16* lB0a = lb[0] + w * 512;
    u16* lB1a = lb[0] + 2048 + w * 512;
    u16* lA0b = la[1] + w * 512;
    u16* lA1b = la[1] + 2048 + w * 512;
    u16* lB0b = lb[1] + w * 512;
    u16* lB1b = lb[1] + 2048 + w * 512;

    f32x4 acc[4][4] = {};
    int row16 = lane & 15, q8 = (lane >> 4) * 8;

    for (int k0 = 0; k0 < KC; k0 += 64) {
        load_lds16(gA0 + k0, lA0a);
        load_lds16(gA1 + k0, lA1a);
        load_lds16(gB0 + k0, lB0a);
        load_lds16(gB1 + k0, lB1a);
        load_lds16(gA0 + k0 + 32, lA0b);
        load_lds16(gA1 + k0 + 32, lA1b);
        load_lds16(gB0 + k0 + 32, lB0b);
        load_lds16(gB1 + k0 + 32, lB1b);
        __syncthreads();

        #pragma unroll
        for (int h = 0; h < 2; ++h) {
            bf16x8 af[4], bf[4];
            #pragma unroll
            for (int tm = 0; tm < 4; ++tm)
                af[tm] = *(const bf16x8*)&la[h][(wm + tm * 16 + row16) * 32 + q8];
            #pragma unroll
            for (int tn = 0; tn < 4; ++tn)
                bf[tn] = *(const bf16x8*)&lb[h][(wn + tn * 16 + row16) * 32 + q8];
            #pragma unroll
            for (int tm = 0; tm < 4; ++tm)
                #pragma unroll
                for (int tn = 0; tn < 4; ++tn)
                    acc[tm][tn] = __builtin_amdgcn_mfma_f32_16x16x32_bf16(
                        af[tm], bf[tn], acc[tm][tn], 0, 0, 0);
        }
        __syncthreads();
    }

    // D layout: col=lane&15, row=(lane>>4)*4+reg  (m89-verified)
    int col = lane & 15, qr = lane >> 4;
    #pragma unroll
    for (int tm = 0; tm < 4; ++tm) {
        #pragma unroll
        for (int tn = 0; tn < 4; ++tn) {
            int nn = n0 + wn + tn * 16 + col;
            #pragma unroll
            for (int rg = 0; rg < 4; ++rg) {
                int mm = m0 + wm + tm * 16 + qr * 4 + rg;
                unsafeAtomicAdd(&Y[(size_t)mm * N + nn], acc[tm][tn][rg]);
            }
        }
    }
}

// ---------------------------------------------------------------------------
// BN stats stage 1: partial sum/sumsq per 32-row chunk.
// ---------------------------------------------------------------------------
__global__ __launch_bounds__(256) void bn_stats_part_kernel(
    const float* __restrict__ y, float* __restrict__ part, int N) {
    int c4 = blockIdx.x * 256 + (threadIdx.x & 63) * 4;
    int rg = threadIdx.x >> 6;
    int r0 = blockIdx.y * 32;
    float4 s = make_float4(0.f, 0.f, 0.f, 0.f);
    float4 q = make_float4(0.f, 0.f, 0.f, 0.f);
    for (int i = 0; i < 8; ++i) {
        int r = r0 + rg + i * 4;
        float4 v = *(const float4*)&y[(size_t)r * N + c4];
        s.x += v.x; s.y += v.y; s.z += v.z; s.w += v.w;
        q.x += v.x * v.x; q.y += v.y * v.y; q.z += v.z * v.z; q.w += v.w * v.w;
    }
    __shared__ float4 ls[4][64], lq[4][64];
    ls[rg][threadIdx.x & 63] = s;
    lq[rg][threadIdx.x & 63] = q;
    __syncthreads();
    if (rg == 0) {
        int cx = threadIdx.x & 63;
        #pragma unroll
        for (int g = 1; g < 4; ++g) {
            float4 a = ls[g][cx], b = lq[g][cx];
            s.x += a.x; s.y += a.y; s.z += a.z; s.w += a.w;
            q.x += b.x; q.y += b.y; q.z += b.z; q.w += b.w;
        }
        float* po = part + (size_t)blockIdx.y * 2048;
        *(float4*)&po[c4] = s;
        *(float4*)&po[1024 + c4] = q;
    }
}

// ---------------------------------------------------------------------------
// BN stats stage 2: reduce chunks -> mean, rstd.
// ---------------------------------------------------------------------------
__global__ __launch_bounds__(256) void bn_stats_final_kernel(
    const float* __restrict__ part, float* __restrict__ stats, int M, int nchunk) {
    int col = blockIdx.x * 256 + threadIdx.x;
    float s = 0.f, q = 0.f;
    for (int ch = 0; ch < nchunk; ++ch) {
        s += part[(size_t)ch * 2048 + col];
        q += part[(size_t)ch * 2048 + 1024 + col];
    }
    float mean = s / (float)M;
    float var = q / (float)M - mean * mean;
    stats[col] = mean;
    stats[1024 + col] = rsqrtf(var + 1e-5f);
}

// ---------------------------------------------------------------------------
// BN apply + relu -> bf16.  N hardcoded 1024.
// ---------------------------------------------------------------------------
__global__ void bn_apply_kernel(const float* __restrict__ y,
                                const float* __restrict__ stats,
                                const float* __restrict__ g,
                                const float* __restrict__ b,
                                __hip_bfloat16* __restrict__ xo, int total) {
    int idx = blockIdx.x * blockDim.x + threadIdx.x;
    if (idx >= total) return;
    int col = idx & 1023;
    float v = (y[idx] - stats[col]) * stats[1024 + col] * g[col] + b[col];
    xo[idx] = __float2bfloat16(fmaxf(v, 0.f));
}

// ---------------------------------------------------------------------------
extern "C" void kernel_launch(void* const* d_in, const int* in_sizes, int n_in,
                              void* d_out, int out_size, void* d_ws, size_t ws_size,
                              hipStream_t stream) {
    const float* feat0   = (const float*)d_in[0];
    const float* feat1   = (const float*)d_in[1];
    const float* feat2   = (const float*)d_in[2];
    const float* bbox2d  = (const float*)d_in[3];
    const int*   anchor  = (const int*)d_in[4];
    const float* fc1_w   = (const float*)d_in[5];
    const float* bn1_g   = (const float*)d_in[7];
    const float* bn1_b   = (const float*)d_in[8];
    const float* fc2_w   = (const float*)d_in[9];
    const float* bn2_g   = (const float*)d_in[11];
    const float* bn2_b   = (const float*)d_in[12];
    const float* cate_w  = (const float*)d_in[13];
    const float* cate_b  = (const float*)d_in[14];
    const float* bbox3d_w= (const float*)d_in[15];
    const float* bbox3d_b= (const float*)d_in[16];
    const float* yawc_w  = (const float*)d_in[17];
    const float* yawc_b  = (const float*)d_in[18];
    const float* yawr_w  = (const float*)d_in[19];
    const float* yawr_b  = (const float*)d_in[20];
    const float* hgt_w   = (const float*)d_in[21];
    const float* hgt_b   = (const float*)d_in[22];

    const int B = 4, N = 512, FC = 1024;
    const int M = B * N;   // 2048
    const int K1 = 12544;  // 256*49

    // workspace layout (tf* aliased with post-ROI buffers; disjoint lifetimes)
    char* base = (char*)d_ws;
    u16* xb = (u16*)base;                              // 51,380,224 B
    char* ub = base + 51380224;                        // union, 44,040,192 B
    u16* tf0 = (u16*)ub;                               // 33,554,432
    u16* tf1 = (u16*)(ub + 33554432);                  //  8,388,608
    u16* tf2 = (u16*)(ub + 41943040);                  //  2,097,152
    u16* w1t = (u16*)ub;                               // 25,690,112
    u16* w2t = (u16*)(ub + 25690112);                  //  2,097,152
    float* y   = (float*)(ub + 27787264);              //  8,388,608
    u16* x1b = (u16*)(ub + 36175872);                  //  4,194,304 (end 40,370,176)
    float* part = (float*)(ub + 40370176);             //    524,288 (end 40,894,464)
    float* hout = (float*)(ub + 40894464);             //  1,048,576
    char* tail = ub + 44040192;
    float* stats = (float*)tail;                       // 8 KB
    u16*   whT   = (u16*)(tail + 8192);                // 262,144 (128x1024 bf16)
    float* bhd   = (float*)(tail + 8192 + 262144);     // 512
    float* outp  = (float*)d_out;

    // 1. head weight concat -> whT bf16 + bias (independent)
    head_concat_kernel<<<(128 * 1024 + 255) / 256, 256, 0, stream>>>(
        cate_w, bbox3d_w, yawc_w, yawr_w, hgt_w,
        cate_b, bbox3d_b, yawc_b, yawr_b, hgt_b, whT, bhd);

    // 2. fused feature layout transform (B,C,H,W)f32 -> (B,HW,C)bf16
    transpose_feat3_kernel<<<dim3(336, B), 256, 0, stream>>>(
        feat0, feat1, feat2, tf0, tf1, tf2);

    // 3. ROI align -> x bf16 (M, K1), k' = bin*256 + c layout
    roi_align_v3_kernel<<<M, 512, 0, stream>>>(tf0, tf1, tf2, bbox2d, anchor, xb);

    // 4. weight transposes (overwrite tf* region — after roi)
    transpose_w_kernel<<<dim3(K1 / 64, FC / 64), 256, 0, stream>>>(fc1_w, w1t, K1, 1);
    transpose_w_kernel<<<dim3(FC / 64, FC / 64), 256, 0, stream>>>(fc2_w, w2t, FC, 0);

    // 5. fc1 (split-K=4, atomic accumulate into zeroed y) + BN1
    hipMemsetAsync(y, 0, (size_t)M * FC * 4, stream);
    gemm_splitk_kernel<<<dim3(M / 128, FC / 128, 4), 256, 0, stream>>>(
        xb, w1t, y, M, FC, K1, K1 / 4);
    bn_stats_part_kernel<<<dim3(FC / 256, M / 32), 256, 0, stream>>>(y, part, FC);
    bn_stats_final_kernel<<<FC / 256, 256, 0, stream>>>(part, stats, M, M / 32);
    bn_apply_kernel<<<(M * FC + 255) / 256, 256, 0, stream>>>(
        y, stats, bn1_g, bn1_b, (__hip_bfloat16*)x1b, M * FC);

    // 6. fc2 (split-K=4) + BN2
    hipMemsetAsync(y, 0, (size_t)M * FC * 4, stream);
    gemm_splitk_kernel<<<dim3(M / 128, FC / 128, 4), 256, 0, stream>>>(
        x1b, w2t, y, M, FC, FC, FC / 4);
    bn_stats_part_kernel<<<dim3(FC / 256, M / 32), 256, 0, stream>>>(y, part, FC);
    bn_stats_final_kernel<<<FC / 256, 256, 0, stream>>>(part, stats, M, M / 32);
    bn_apply_kernel<<<(M * FC + 255) / 256, 256, 0, stream>>>(
        y, stats, bn2_g, bn2_b, (__hip_bfloat16*)x1b, M * FC);

    // 7. heads via MFMA: hout = bias; hout += x1b @ whT^T; copy 100 cols
    bias_init_kernel<<<(M * 128 + 255) / 256, 256, 0, stream>>>(hout, bhd, M * 128);
    gemm_splitk_kernel<<<dim3(M / 128, 1, 8), 256, 0, stream>>>(
        x1b, whT, hout, M, 128, FC, FC / 8);
    copy100_kernel<<<(M * 100 + 255) / 256, 256, 0, stream>>>(hout, outp, M * 100);
}

// Round 8
// 439.584 us; speedup vs baseline: 1.1936x; 1.0319x over previous
//
#include <hip/hip_runtime.h>
#include <hip/hip_bf16.h>

typedef unsigned short u16;
typedef unsigned int u32;
typedef __bf16 bf16x8 __attribute__((ext_vector_type(8)));
typedef float f32x4 __attribute__((ext_vector_type(4)));

#define RESOLUTION 7
#define SR 2
#define SS 14
#define NSAMP 196

static __device__ __forceinline__ u16 f2bf(float f) {
    __hip_bfloat16 t = __float2bfloat16(f);
    return *reinterpret_cast<u16*>(&t);
}
static __device__ __forceinline__ float bf2f(u16 h) {
    return __uint_as_float(((u32)h) << 16);
}

// async global->LDS, 16B per lane; lds dest is wave-uniform base + lane*16
// [m97/m104-verified pattern]
static __device__ __forceinline__ void load_lds16(const u16* g, u16* l) {
    __builtin_amdgcn_global_load_lds(
        (const __attribute__((address_space(1))) unsigned int*)g,
        (__attribute__((address_space(3))) unsigned int*)l, 16, 0, 0);
}

// ---------------------------------------------------------------------------
// fused feat transpose: (B,C,H,W) f32 -> (B,HW,C) bf16 for all 3 levels.
// float4 reads: lane covers 4 hw, wave covers 4 c-rows x 256 B contiguous.
// ---------------------------------------------------------------------------
__global__ __launch_bounds__(256) void transpose_feat3_kernel(
    const float* __restrict__ f0, const float* __restrict__ f1,
    const float* __restrict__ f2, u16* __restrict__ tf0,
    u16* __restrict__ tf1, u16* __restrict__ tf2) {
    int b = blockIdx.y;
    int bx = blockIdx.x;
    const float* in;
    u16* out;
    int HW, hw0;
    if (bx < 256)      { in = f0; out = tf0; HW = 16384; hw0 = bx * 64; }
    else if (bx < 320) { in = f1; out = tf1; HW = 4096;  hw0 = (bx - 256) * 64; }
    else               { in = f2; out = tf2; HW = 1024;  hw0 = (bx - 320) * 64; }

    __shared__ u16 tile[256][65];
    int hw4 = (threadIdx.x & 15) * 4;
    int cs = threadIdx.x >> 4;  // 0..15
    for (int cc = 0; cc < 256; cc += 16) {
        int c = cc + cs;
        float4 v = *(const float4*)&in[((size_t)(b * 256 + c)) * HW + hw0 + hw4];
        tile[c][hw4 + 0] = f2bf(v.x);
        tile[c][hw4 + 1] = f2bf(v.y);
        tile[c][hw4 + 2] = f2bf(v.z);
        tile[c][hw4 + 3] = f2bf(v.w);
    }
    __syncthreads();

    int ro = threadIdx.x >> 5;
    int co = (threadIdx.x & 31) * 8;
    for (int i = 0; i < 64; i += 8) {
        int hw = i + ro;
        union { uint4 v; u16 h[8]; } o;
        #pragma unroll
        for (int j = 0; j < 8; ++j) o.h[j] = tile[co + j][hw];
        *(uint4*)&out[((size_t)b * HW + hw0 + hw) * 256 + co] = o.v;
    }
}

// ---------------------------------------------------------------------------
// weight transpose: out (N=1024, K) bf16 = in (K, 1024) f32,
// optional k-permutation  k = (kp&255)*49 + (kp>>8).  float4 reads.
// ---------------------------------------------------------------------------
__global__ __launch_bounds__(256) void transpose_w_kernel(
    const float* __restrict__ in, u16* __restrict__ out, int K, int perm) {
    int kp0 = blockIdx.x * 64, n0 = blockIdx.y * 64;
    __shared__ u16 tile[64][65];

    int nn4 = (threadIdx.x & 15) * 4;
    int ks = threadIdx.x >> 4;  // 0..15
    for (int i = 0; i < 64; i += 16) {
        int kp = kp0 + ks + i;
        int k = perm ? ((kp & 255) * 49 + (kp >> 8)) : kp;
        float4 v = *(const float4*)&in[(size_t)k * 1024 + n0 + nn4];
        tile[ks + i][nn4 + 0] = f2bf(v.x);
        tile[ks + i][nn4 + 1] = f2bf(v.y);
        tile[ks + i][nn4 + 2] = f2bf(v.z);
        tile[ks + i][nn4 + 3] = f2bf(v.w);
    }
    __syncthreads();

    int nw = threadIdx.x >> 3, ko = (threadIdx.x & 7) * 8;
    for (int i = 0; i < 2; ++i) {
        int n = nw + i * 32;
        union { uint4 v; u16 h[8]; } o;
        #pragma unroll
        for (int j = 0; j < 8; ++j) o.h[j] = tile[ko + j][n];
        *(uint4*)&out[(size_t)(n0 + n) * K + kp0 + ko] = o.v;
    }
}

// ---------------------------------------------------------------------------
// concat head weights -> whT bf16 (128 rows x 1024 k; rows 100..127 zero)
// + bias (100 f32)
// ---------------------------------------------------------------------------
__global__ void head_concat_kernel(
    const float* __restrict__ cate_w, const float* __restrict__ bbox3d_w,
    const float* __restrict__ yawc_w, const float* __restrict__ yawr_w,
    const float* __restrict__ hgt_w,
    const float* __restrict__ cate_b, const float* __restrict__ bbox3d_b,
    const float* __restrict__ yawc_b, const float* __restrict__ yawr_b,
    const float* __restrict__ hgt_b,
    u16* __restrict__ whT, float* __restrict__ bh) {
    int idx = blockIdx.x * blockDim.x + threadIdx.x;
    if (idx < 128 * 1024) {
        int n = idx >> 10, k = idx & 1023;
        float v = 0.f;
        if (n < 4)        v = cate_w[k * 4 + n];
        else if (n < 22)  v = bbox3d_w[k * 18 + (n - 4)];
        else if (n < 58)  v = yawc_w[k * 36 + (n - 22)];
        else if (n < 94)  v = yawr_w[k * 36 + (n - 58)];
        else if (n < 100) v = hgt_w[k * 6 + (n - 94)];
        whT[idx] = f2bf(v);
    }
    if (idx < 100) {
        int c = idx;
        float v;
        if (c < 4)        v = cate_b[c];
        else if (c < 22)  v = bbox3d_b[c - 4];
        else if (c < 58)  v = yawc_b[c - 22];
        else if (c < 94)  v = yawr_b[c - 58];
        else              v = hgt_b[c - 94];
        bh[c] = v;
    }
}

// ---------------------------------------------------------------------------
// ROI align v3 on (B,HW,C) bf16 feats.  x row layout: k' = bin*256 + c.
// 512 threads = 16 groups of 32 lanes; <=4 bins per group.
// ---------------------------------------------------------------------------
__global__ __launch_bounds__(512) void roi_align_v3_kernel(
    const u16* __restrict__ tf0, const u16* __restrict__ tf1,
    const u16* __restrict__ tf2, const float* __restrict__ bbox2d,
    const int* __restrict__ anchor_id, u16* __restrict__ xb) {
    int bn = blockIdx.x;
    int b = bn >> 9;
    int tid = threadIdx.x;

    __shared__ int s_o00[NSAMP], s_o01[NSAMP], s_o10[NSAMP], s_o11[NSAMP];
    __shared__ float s_w00[NSAMP], s_w01[NSAMP], s_w10[NSAMP], s_w11[NSAMP];

    float cy = bbox2d[bn * 4 + 0], cx = bbox2d[bn * 4 + 1];
    float hh = bbox2d[bn * 4 + 2], ww = bbox2d[bn * 4 + 3];
    int lvl = anchor_id[bn] / 3;
    float scale = (lvl == 0) ? 0.25f : ((lvl == 1) ? 0.125f : 0.0625f);
    int H = (lvl == 0) ? 128 : ((lvl == 1) ? 64 : 32);
    int W = H;

    float t = cy - hh * 0.5f, l = cx - ww * 0.5f;
    float btm = cy + hh * 0.5f, r = cx + ww * 0.5f;
    float sy = t * scale - 0.5f, sx = l * scale - 0.5f;
    float bh = (btm - t) * scale * (1.0f / RESOLUTION);
    float bw = (r - l) * scale * (1.0f / RESOLUTION);

    if (tid < NSAMP) {
        int i = tid / SS, j = tid % SS;
        float gi = (i + 0.5f) * (1.0f / SR);
        float gj = (j + 0.5f) * (1.0f / SR);
        float y = sy + gi * bh, x = sx + gj * bw;
        float valid = (y > -1.0f && y < (float)H && x > -1.0f && x < (float)W)
                          ? 0.25f : 0.0f;
        y = fminf(fmaxf(y, 0.0f), (float)(H - 1));
        x = fminf(fmaxf(x, 0.0f), (float)(W - 1));
        int y0 = (int)floorf(y), x0 = (int)floorf(x);
        int y1 = min(y0 + 1, H - 1), x1 = min(x0 + 1, W - 1);
        float ly = y - (float)y0, lx = x - (float)x0;
        float hy = 1.f - ly, hx = 1.f - lx;
        s_o00[tid] = (y0 * W + x0) * 256;
        s_o01[tid] = (y0 * W + x1) * 256;
        s_o10[tid] = (y1 * W + x0) * 256;
        s_o11[tid] = (y1 * W + x1) * 256;
        s_w00[tid] = hy * hx * valid;
        s_w01[tid] = hy * lx * valid;
        s_w10[tid] = ly * hx * valid;
        s_w11[tid] = ly * lx * valid;
    }
    __syncthreads();

    const u16* fb = (lvl == 0) ? (tf0 + (size_t)b * 16384 * 256)
                  : (lvl == 1) ? (tf1 + (size_t)b * 4096 * 256)
                               : (tf2 + (size_t)b * 1024 * 256);
    int g = tid >> 5;
    int c0 = (tid & 31) * 8;
    u16* xr = xb + (size_t)bn * 12544;

    #pragma unroll
    for (int ii = 0; ii < 4; ++ii) {
        int bin = g + ii * 16;
        if (bin < 49) {
            int ph = bin / 7, pw = bin % 7;
            float a[8] = {0.f, 0.f, 0.f, 0.f, 0.f, 0.f, 0.f, 0.f};
            #pragma unroll
            for (int dy = 0; dy < SR; ++dy) {
                #pragma unroll
                for (int dx = 0; dx < SR; ++dx) {
                    int si = (ph * SR + dy) * SS + (pw * SR + dx);
                    int o00 = s_o00[si], o01 = s_o01[si];
                    int o10 = s_o10[si], o11 = s_o11[si];
                    float w00 = s_w00[si], w01 = s_w01[si];
                    float w10 = s_w10[si], w11 = s_w11[si];
                    union { uint4 v; u16 h[8]; } u0, u1, u2, u3;
                    u0.v = *(const uint4*)(fb + o00 + c0);
                    u1.v = *(const uint4*)(fb + o01 + c0);
                    u2.v = *(const uint4*)(fb + o10 + c0);
                    u3.v = *(const uint4*)(fb + o11 + c0);
                    #pragma unroll
                    for (int j = 0; j < 8; ++j) {
                        a[j] = fmaf(bf2f(u0.h[j]), w00, a[j]);
                        a[j] = fmaf(bf2f(u1.h[j]), w01, a[j]);
                        a[j] = fmaf(bf2f(u2.h[j]), w10, a[j]);
                        a[j] = fmaf(bf2f(u3.h[j]), w11, a[j]);
                    }
                }
            }
            union { uint4 v; u16 h[8]; } o;
            #pragma unroll
            for (int j = 0; j < 8; ++j) o.h[j] = f2bf(a[j]);
            *(uint4*)&xr[bin * 256 + c0] = o.v;
        }
    }
}

// ---------------------------------------------------------------------------
// hout(2048,128) init: bias for n<100, 0 above
// ---------------------------------------------------------------------------
__global__ void bias_init_kernel(float* __restrict__ hout,
                                 const float* __restrict__ bh, int total) {
    int idx = blockIdx.x * blockDim.x + threadIdx.x;
    if (idx >= total) return;
    int n = idx & 127;
    hout[idx] = (n < 100) ? bh[n] : 0.f;
}

// ---------------------------------------------------------------------------
// copy hout(2048,128) cols [0,100) -> d_out(2048,100)
// ---------------------------------------------------------------------------
__global__ void copy100_kernel(const float* __restrict__ hout,
                               float* __restrict__ out, int total) {
    int idx = blockIdx.x * blockDim.x + threadIdx.x;
    if (idx >= total) return;
    int m = idx / 100, n = idx - m * 100;
    out[idx] = hout[m * 128 + n];
}

// ---------------------------------------------------------------------------
// 128x128 MFMA GEMM, split-K + atomic accumulation, BK=64 double-stage:
// 32 MFMAs per barrier pair; 32 KB LDS.  split-K=4 measured sweet spot.
// ---------------------------------------------------------------------------
__global__ __launch_bounds__(256) void gemm_splitk_kernel(
    const u16* __restrict__ A, const u16* __restrict__ BT,
    float* __restrict__ Y, int M, int N, int K, int KC) {
    __shared__ u16 la[2][128 * 32];
    __shared__ u16 lb[2][128 * 32];
    int m0 = blockIdx.x * 128;
    int n0 = blockIdx.y * 128;
    int kbeg = blockIdx.z * KC;
    int tid = threadIdx.x;
    int w = tid >> 6, lane = tid & 63;
    int wm = (w >> 1) * 64, wn = (w & 1) * 64;

    int idx1 = tid + 256;
    const u16* gA0 = A + (size_t)(m0 + (tid >> 2)) * K + (tid & 3) * 8 + kbeg;
    const u16* gA1 = A + (size_t)(m0 + (idx1 >> 2)) * K + (idx1 & 3) * 8 + kbeg;
    const u16* gB0 = BT + (size_t)(n0 + (tid >> 2)) * K + (tid & 3) * 8 + kbeg;
    const u16* gB1 = BT + (size_t)(n0 + (idx1 >> 2)) * K + (idx1 & 3) * 8 + kbeg;
    u16* lA0a = la[0] + w * 512;
    u16* lA1a = la[0] + 2048 + w * 512;
    u16* lB0a = lb[0] + w * 512;
    u16* lB1a = lb[0] + 2048 + w * 512;
    u16* lA0b = la[1] + w * 512;
    u16* lA1b = la[1] + 2048 + w * 512;
    u16* lB0b = lb[1] + w * 512;
    u16* lB1b = lb[1] + 2048 + w * 512;

    f32x4 acc[4][4] = {};
    int row16 = lane & 15, q8 = (lane >> 4) * 8;

    for (int k0 = 0; k0 < KC; k0 += 64) {
        load_lds16(gA0 + k0, lA0a);
        load_lds16(gA1 + k0, lA1a);
        load_lds16(gB0 + k0, lB0a);
        load_lds16(gB1 + k0, lB1a);
        load_lds16(gA0 + k0 + 32, lA0b);
        load_lds16(gA1 + k0 + 32, lA1b);
        load_lds16(gB0 + k0 + 32, lB0b);
        load_lds16(gB1 + k0 + 32, lB1b);
        __syncthreads();

        #pragma unroll
        for (int h = 0; h < 2; ++h) {
            bf16x8 af[4], bf[4];
            #pragma unroll
            for (int tm = 0; tm < 4; ++tm)
                af[tm] = *(const bf16x8*)&la[h][(wm + tm * 16 + row16) * 32 + q8];
            #pragma unroll
            for (int tn = 0; tn < 4; ++tn)
                bf[tn] = *(const bf16x8*)&lb[h][(wn + tn * 16 + row16) * 32 + q8];
            #pragma unroll
            for (int tm = 0; tm < 4; ++tm)
                #pragma unroll
                for (int tn = 0; tn < 4; ++tn)
                    acc[tm][tn] = __builtin_amdgcn_mfma_f32_16x16x32_bf16(
                        af[tm], bf[tn], acc[tm][tn], 0, 0, 0);
        }
        __syncthreads();
    }

    // D layout: col=lane&15, row=(lane>>4)*4+reg  (m89-verified)
    int col = lane & 15, qr = lane >> 4;
    #pragma unroll
    for (int tm = 0; tm < 4; ++tm) {
        #pragma unroll
        for (int tn = 0; tn < 4; ++tn) {
            int nn = n0 + wn + tn * 16 + col;
            #pragma unroll
            for (int rg = 0; rg < 4; ++rg) {
                int mm = m0 + wm + tm * 16 + qr * 4 + rg;
                unsafeAtomicAdd(&Y[(size_t)mm * N + nn], acc[tm][tn][rg]);
            }
        }
    }
}

// ---------------------------------------------------------------------------
// BN stats stage 1: partial sum/sumsq per 32-row chunk.
// ---------------------------------------------------------------------------
__global__ __launch_bounds__(256) void bn_stats_part_kernel(
    const float* __restrict__ y, float* __restrict__ part, int N) {
    int c4 = blockIdx.x * 256 + (threadIdx.x & 63) * 4;
    int rg = threadIdx.x >> 6;
    int r0 = blockIdx.y * 32;
    float4 s = make_float4(0.f, 0.f, 0.f, 0.f);
    float4 q = make_float4(0.f, 0.f, 0.f, 0.f);
    for (int i = 0; i < 8; ++i) {
        int r = r0 + rg + i * 4;
        float4 v = *(const float4*)&y[(size_t)r * N + c4];
        s.x += v.x; s.y += v.y; s.z += v.z; s.w += v.w;
        q.x += v.x * v.x; q.y += v.y * v.y; q.z += v.z * v.z; q.w += v.w * v.w;
    }
    __shared__ float4 ls[4][64], lq[4][64];
    ls[rg][threadIdx.x & 63] = s;
    lq[rg][threadIdx.x & 63] = q;
    __syncthreads();
    if (rg == 0) {
        int cx = threadIdx.x & 63;
        #pragma unroll
        for (int g = 1; g < 4; ++g) {
            float4 a = ls[g][cx], b = lq[g][cx];
            s.x += a.x; s.y += a.y; s.z += a.z; s.w += a.w;
            q.x += b.x; q.y += b.y; q.z += b.z; q.w += b.w;
        }
        float* po = part + (size_t)blockIdx.y * 2048;
        *(float4*)&po[c4] = s;
        *(float4*)&po[1024 + c4] = q;
    }
}

// ---------------------------------------------------------------------------
// BN stats stage 2: reduce chunks -> mean, rstd.
// ---------------------------------------------------------------------------
__global__ __launch_bounds__(256) void bn_stats_final_kernel(
    const float* __restrict__ part, float* __restrict__ stats, int M, int nchunk) {
    int col = blockIdx.x * 256 + threadIdx.x;
    float s = 0.f, q = 0.f;
    for (int ch = 0; ch < nchunk; ++ch) {
        s += part[(size_t)ch * 2048 + col];
        q += part[(size_t)ch * 2048 + 1024 + col];
    }
    float mean = s / (float)M;
    float var = q / (float)M - mean * mean;
    stats[col] = mean;
    stats[1024 + col] = rsqrtf(var + 1e-5f);
}

// ---------------------------------------------------------------------------
// BN apply + relu -> bf16, float4-vectorized (4 elems/thread), optionally
// zeroing y in the same pass (replaces the next GEMM's memset).
// N hardcoded 1024.
// ---------------------------------------------------------------------------
__global__ void bn_apply_kernel(float* __restrict__ y,
                                const float* __restrict__ stats,
                                const float* __restrict__ g,
                                const float* __restrict__ b,
                                u16* __restrict__ xo, int total4, int zero_y) {
    int idx = blockIdx.x * blockDim.x + threadIdx.x;
    if (idx >= total4) return;
    int e0 = idx * 4;
    int col = e0 & 1023;
    float4 v = *(const float4*)&y[e0];
    float4 mu = *(const float4*)&stats[col];
    float4 rs = *(const float4*)&stats[1024 + col];
    float4 gg = *(const float4*)&g[col];
    float4 bb = *(const float4*)&b[col];
    ushort4 o;
    o.x = f2bf(fmaxf((v.x - mu.x) * rs.x * gg.x + bb.x, 0.f));
    o.y = f2bf(fmaxf((v.y - mu.y) * rs.y * gg.y + bb.y, 0.f));
    o.z = f2bf(fmaxf((v.z - mu.z) * rs.z * gg.z + bb.z, 0.f));
    o.w = f2bf(fmaxf((v.w - mu.w) * rs.w * gg.w + bb.w, 0.f));
    *(ushort4*)&xo[e0] = o;
    if (zero_y)
        *(float4*)&y[e0] = make_float4(0.f, 0.f, 0.f, 0.f);
}

// ---------------------------------------------------------------------------
extern "C" void kernel_launch(void* const* d_in, const int* in_sizes, int n_in,
                              void* d_out, int out_size, void* d_ws, size_t ws_size,
                              hipStream_t stream) {
    const float* feat0   = (const float*)d_in[0];
    const float* feat1   = (const float*)d_in[1];
    const float* feat2   = (const float*)d_in[2];
    const float* bbox2d  = (const float*)d_in[3];
    const int*   anchor  = (const int*)d_in[4];
    const float* fc1_w   = (const float*)d_in[5];
    const float* bn1_g   = (const float*)d_in[7];
    const float* bn1_b   = (const float*)d_in[8];
    const float* fc2_w   = (const float*)d_in[9];
    const float* bn2_g   = (const float*)d_in[11];
    const float* bn2_b   = (const float*)d_in[12];
    const float* cate_w  = (const float*)d_in[13];
    const float* cate_b  = (const float*)d_in[14];
    const float* bbox3d_w= (const float*)d_in[15];
    const float* bbox3d_b= (const float*)d_in[16];
    const float* yawc_w  = (const float*)d_in[17];
    const float* yawc_b  = (const float*)d_in[18];
    const float* yawr_w  = (const float*)d_in[19];
    const float* yawr_b  = (const float*)d_in[20];
    const float* hgt_w   = (const float*)d_in[21];
    const float* hgt_b   = (const float*)d_in[22];

    const int B = 4, N = 512, FC = 1024;
    const int M = B * N;   // 2048
    const int K1 = 12544;  // 256*49

    // workspace layout (tf* aliased with post-ROI buffers; disjoint lifetimes)
    char* base = (char*)d_ws;
    u16* xb = (u16*)base;                              // 51,380,224 B
    char* ub = base + 51380224;                        // union, 44,040,192 B
    u16* tf0 = (u16*)ub;                               // 33,554,432
    u16* tf1 = (u16*)(ub + 33554432);                  //  8,388,608
    u16* tf2 = (u16*)(ub + 41943040);                  //  2,097,152
    u16* w1t = (u16*)ub;                               // 25,690,112
    u16* w2t = (u16*)(ub + 25690112);                  //  2,097,152
    float* y   = (float*)(ub + 27787264);              //  8,388,608
    u16* x1b = (u16*)(ub + 36175872);                  //  4,194,304 (end 40,370,176)
    float* part = (float*)(ub + 40370176);             //    524,288 (end 40,894,464)
    float* hout = (float*)(ub + 40894464);             //  1,048,576
    char* tail = ub + 44040192;
    float* stats = (float*)tail;                       // 8 KB
    u16*   whT   = (u16*)(tail + 8192);                // 262,144 (128x1024 bf16)
    float* bhd   = (float*)(tail + 8192 + 262144);     // 512
    float* outp  = (float*)d_out;

    // 1. head weight concat -> whT bf16 + bias (independent)
    head_concat_kernel<<<(128 * 1024 + 255) / 256, 256, 0, stream>>>(
        cate_w, bbox3d_w, yawc_w, yawr_w, hgt_w,
        cate_b, bbox3d_b, yawc_b, yawr_b, hgt_b, whT, bhd);

    // 2. fused feature layout transform (B,C,H,W)f32 -> (B,HW,C)bf16
    transpose_feat3_kernel<<<dim3(336, B), 256, 0, stream>>>(
        feat0, feat1, feat2, tf0, tf1, tf2);

    // 3. ROI align -> x bf16 (M, K1), k' = bin*256 + c layout
    roi_align_v3_kernel<<<M, 512, 0, stream>>>(tf0, tf1, tf2, bbox2d, anchor, xb);

    // 4. weight transposes (overwrite tf* region — after roi)
    transpose_w_kernel<<<dim3(K1 / 64, FC / 64), 256, 0, stream>>>(fc1_w, w1t, K1, 1);
    transpose_w_kernel<<<dim3(FC / 64, FC / 64), 256, 0, stream>>>(fc2_w, w2t, FC, 0);

    // 5. fc1 (split-K=4, atomic accumulate into zeroed y) + BN1
    hipMemsetAsync(y, 0, (size_t)M * FC * 4, stream);
    gemm_splitk_kernel<<<dim3(M / 128, FC / 128, 4), 256, 0, stream>>>(
        xb, w1t, y, M, FC, K1, K1 / 4);
    bn_stats_part_kernel<<<dim3(FC / 256, M / 32), 256, 0, stream>>>(y, part, FC);
    bn_stats_final_kernel<<<FC / 256, 256, 0, stream>>>(part, stats, M, M / 32);
    bn_apply_kernel<<<(M * FC / 4 + 255) / 256, 256, 0, stream>>>(
        y, stats, bn1_g, bn1_b, x1b, M * FC / 4, 1);  // zero y for fc2

    // 6. fc2 (split-K=4) + BN2
    gemm_splitk_kernel<<<dim3(M / 128, FC / 128, 4), 256, 0, stream>>>(
        x1b, w2t, y, M, FC, FC, FC / 4);
    bn_stats_part_kernel<<<dim3(FC / 256, M / 32), 256, 0, stream>>>(y, part, FC);
    bn_stats_final_kernel<<<FC / 256, 256, 0, stream>>>(part, stats, M, M / 32);
    bn_apply_kernel<<<(M * FC / 4 + 255) / 256, 256, 0, stream>>>(
        y, stats, bn2_g, bn2_b, x1b, M * FC / 4, 0);

    // 7. heads via MFMA: hout = bias; hout += x1b @ whT^T; copy 100 cols
    bias_init_kernel<<<(M * 128 + 255) / 256, 256, 0, stream>>>(hout, bhd, M * 128);
    gemm_splitk_kernel<<<dim3(M / 128, 1, 8), 256, 0, stream>>>(
        x1b, whT, hout, M, 128, FC, FC / 8);
    copy100_kernel<<<(M * 100 + 255) / 256, 256, 0, stream>>>(hout, outp, M * 100);
}